// Round 18
// baseline (210.938 us; speedup 1.0000x reference)
//
#include <hip/hip_runtime.h>
#include <cmath>

#define IMG_H 512
#define IMG_W 512
#define TH 16            // tile rows (4 waves x 4 rows)
#define TW 118           // output cols per block
#define SC 128           // stored cols = TW + 10 halo = exactly 2 lane passes
#define LDSW 131         // ODD element stride, >=130 so k<=17 reads stay in-bounds
#define GX 5             // ceil(512 / 118); last block outputs 40 cols (masked)
#define NPLANES 96       // 32 batch * 3 channels
#define NPIX 25165824.0  // 96*512*512

typedef float vf2 __attribute__((ext_vector_type(2)));

struct GaussW { float w[11]; };

// 4-array algebraic form (round 11): convolve (A,B),(T,S), T=a^2+b^2.
// Round 18: WAVE-UNIFORM ROWS. Each wave owns 4 output rows -> row index,
// bounds check, and row base pointer are all SALU (s_cmp/s_cbranch/s_add);
// global loads are SGPR-base + lane col offset = ZERO per-load VALU.
// (Round 17 showed per-load clamp/mask/addr VALU ~= the tap work itself.)
// Out-of-range rows: uniform skip (exact zero-padding). Out-of-range cols:
// vertical conv of a zeroed column == 0 -> mask the OUTPUT at write (8 pk).
__global__ __launch_bounds__(256, 4) void ssim_main(
    const float* __restrict__ img1, const float* __restrict__ img2,
    float* __restrict__ partials, GaussW gw, int use_atomic, float* __restrict__ out)
{
    __shared__ vf2 VAB[TH][LDSW];   // 16*131*8 = 16768 B
    __shared__ vf2 VTS[TH][LDSW];   // 16768 B  (total ~33.6 KB -> 4 blocks/CU)
    __shared__ float wsum[4];

    const int tid = threadIdx.x;
    const int lane = tid & 63;
    const int wid = __builtin_amdgcn_readfirstlane(tid >> 6);   // force SGPR
    const int plane = blockIdx.z;
    const int tr0 = blockIdx.y * TH;
    const int tc0 = blockIdx.x * TW;
    const float* __restrict__ plane1 = img1 + ((size_t)plane << 18);
    const float* __restrict__ plane2 = img2 + ((size_t)plane << 18);

    // ---------------- Phase 1: vertical conv, wave-uniform rows ---------------
    // Wave wid: output rows r0..r0+3 (r0 = 4*wid), input rows r0-5..r0+8 (14).
    // 2 column passes x 64 lanes = 128 stored cols, all lanes always active.
    {
        const int r0 = wid * 4;
        #pragma unroll
        for (int pass = 0; pass < 2; ++pass) {
            const int sc = pass * 64 + lane;          // stored col 0..127
            const int gc = tc0 + sc - 5;
            const float cmask = ((unsigned)gc < IMG_W) ? 1.f : 0.f;
            const int gcc = min(max(gc, 0), IMG_W - 1);   // per-lane, once/pass

            vf2 aAB[4], aTS[4];
            #pragma unroll
            for (int o = 0; o < 4; ++o) { aAB[o] = (vf2){0.f, 0.f}; aTS[o] = (vf2){0.f, 0.f}; }

            #pragma unroll
            for (int ii = 0; ii < 14; ++ii) {
                const int gr = tr0 + r0 - 5 + ii;     // SALU chain
                if ((unsigned)gr < (unsigned)IMG_H) { // wave-uniform s_cbranch
                    const float* __restrict__ r1 = plane1 + ((size_t)gr << 9);
                    const float* __restrict__ r2 = plane2 + ((size_t)gr << 9);
                    const float a = r1[gcc];          // global_load v,voff,s[base]
                    const float b = r2[gcc];
                    const vf2 ab = { a, b };
                    const vf2 pq = ab * ab;                    // v_pk_mul_f32
                    const vf2 ts = { pq.x + pq.y, a * b };     // (a^2+b^2, a*b)
                    #pragma unroll
                    for (int o = 0; o < 4; ++o) {
                        if (o <= ii && ii <= o + 10) {          // compile-time
                            const float wt = gw.w[ii - o];
                            const vf2 wtv = { wt, wt };
                            aAB[o] = __builtin_elementwise_fma(wtv, ab, aAB[o]);
                            aTS[o] = __builtin_elementwise_fma(wtv, ts, aTS[o]);
                        }
                    }
                }
            }
            const vf2 cm = { cmask, cmask };
            #pragma unroll
            for (int o = 0; o < 4; ++o) {
                VAB[r0 + o][sc] = aAB[o] * cm;        // ds_write_b64
                VTS[r0 + o][sc] = aTS[o] * cm;
            }
        }
    }
    __syncthreads();

    // ---------------- Phase 2: horizontal conv, packed per-column scatter -----
    // r = tid&15 (low bits): b64 pair (131r + c0 + k) mod 16 = (3r + ...) is a
    // bijection over r -> all 16 pairs x2 per half-wave = hw minimum.
    // Outputs beyond TW (or image edge for the last x-block) masked by select;
    // their window reads (stored cols up to 129 < LDSW) stay in-bounds.
    float lsum = 0.f;
    {
        const int r = tid & 15;
        const int c0 = (tid >> 4) * 8;               // output col group 0..120
        const vf2* __restrict__ bAB = &VAB[r][c0];
        const vf2* __restrict__ bTS = &VTS[r][c0];
        const int cvalid = min(TW, IMG_W - tc0);     // 118, or 40 for last block

        vf2 mAB[8], eTS[8];
        #pragma unroll
        for (int k = 0; k <= 17; ++k) {              // stored cols c0 .. c0+17
            const vf2 vab = bAB[k];                  // ds_read_b64, imm offset
            const vf2 vts = bTS[k];
            #pragma unroll
            for (int c = 0; c < 8; ++c) {
                if (c <= k && k <= c + 10) {                 // compile-time
                    const float wt = gw.w[k - c];
                    const vf2 wtv = { wt, wt };
                    if (k == c) {                             // first touch
                        mAB[c] = wtv * vab;
                        eTS[c] = wtv * vts;
                    } else {
                        mAB[c] = __builtin_elementwise_fma(wtv, vab, mAB[c]);
                        eTS[c] = __builtin_elementwise_fma(wtv, vts, eTS[c]);
                    }
                }
            }
        }
        #pragma unroll
        for (int c = 0; c < 8; ++c) {
            const float a1 = mAB[c].x, a2 = mAB[c].y;   // mu1, mu2
            const float T  = eTS[c].x, S = eTS[c].y;    // conv(a^2+b^2), conv(ab)
            const float h    = fmaf(a1, a1, a2 * a2);   // mu11 + mu22
            const float mu12 = a1 * a2;
            const float num  = fmaf(2.f, mu12, 0.0001f)
                             * fmaf(2.f, S - mu12, 0.0009f);
            const float den  = (h + 0.0001f) * ((T - h) + 0.0009f);
            const float val  = num * __builtin_amdgcn_rcpf(den);  // rcp ~1ulp
            lsum += (c0 + c < cvalid) ? val : 0.f;   // select guards garbage too
        }
    }
    // block reduction
    #pragma unroll
    for (int off = 32; off; off >>= 1) lsum += __shfl_down(lsum, off, 64);
    if ((tid & 63) == 0) wsum[tid >> 6] = lsum;
    __syncthreads();
    if (tid == 0) {
        const float bs = wsum[0] + wsum[1] + wsum[2] + wsum[3];
        if (use_atomic) {
            atomicAdd(out, bs * (float)(1.0 / NPIX));
        } else {
            const int bId = (blockIdx.z * gridDim.y + blockIdx.y) * gridDim.x + blockIdx.x;
            partials[bId] = bs;
        }
    }
}

__global__ __launch_bounds__(256) void ssim_reduce(
    const float* __restrict__ partials, int n, float* __restrict__ out)
{
    const int tid = threadIdx.x;
    double s = 0.0;
    for (int i = tid; i < n; i += 256) s += (double)partials[i];
    #pragma unroll
    for (int off = 32; off; off >>= 1) s += __shfl_down(s, off, 64);
    __shared__ double ws[4];
    if ((tid & 63) == 0) ws[tid >> 6] = s;
    __syncthreads();
    if (tid == 0) out[0] = (float)(((ws[0] + ws[1]) + (ws[2] + ws[3])) / NPIX);
}

extern "C" void kernel_launch(void* const* d_in, const int* in_sizes, int n_in,
                              void* d_out, int out_size, void* d_ws, size_t ws_size,
                              hipStream_t stream) {
    const float* img1 = (const float*)d_in[0];
    const float* img2 = (const float*)d_in[1];
    float* out = (float*)d_out;

    // Gaussian window (host, double precision, normalized)
    GaussW gw;
    {
        double g[11], sum = 0.0;
        for (int i = 0; i < 11; ++i) {
            const double c = (double)(i - 5);
            g[i] = std::exp(-(c * c) / 4.5);   // 2*sigma^2 = 4.5
            sum += g[i];
        }
        for (int i = 0; i < 11; ++i) gw.w[i] = (float)(g[i] / sum);
    }

    dim3 grid(GX, IMG_H / TH, NPLANES);   // 5 x 32 x 96 = 15360
    const int nPart = grid.x * grid.y * grid.z;

    if (ws_size >= (size_t)nPart * sizeof(float)) {
        // deterministic two-stage reduction
        ssim_main<<<grid, 256, 0, stream>>>(img1, img2, (float*)d_ws, gw, 0, out);
        ssim_reduce<<<1, 256, 0, stream>>>((float*)d_ws, nPart, out);
    } else {
        // fallback: atomic accumulation (still within tolerance)
        hipMemsetAsync(d_out, 0, sizeof(float), stream);
        ssim_main<<<grid, 256, 0, stream>>>(img1, img2, nullptr, gw, 1, out);
    }
}

// Round 19
// 90.141 us; speedup vs baseline: 2.3401x; 2.3401x over previous
//
#include <hip/hip_runtime.h>
#include <cmath>

#define IMG_H 512
#define IMG_W 512
#define TH 32            // tile rows (proven base)
#define TW 64            // tile cols
#define LDSW 75          // ODD element stride (load-bearing!); 74 used cols + 1 pad
#define NPLANES 96       // 32 batch * 3 channels
#define NPIX 25165824.0  // 96*512*512

typedef float vf2 __attribute__((ext_vector_type(2)));

struct GaussW { float w[11]; };

// ROUND-13 CONFIGURATION (empirical optimum, 90.7 us wall).
// 4-array algebraic form: convolve (A,B) and (T,S), T = a^2+b^2:
//   den = (mu1^2+mu2^2+C1) * ((conv(T) - mu1^2 - mu2^2) + C2)
// Proven invariants: 11 rows/thread (1.9 loads/row), issue-clustered 42-load
// stream (sched_barrier), 52-VGPR natural allocation, 4 blocks/CU, odd-75
// stride (bank-free), pk_fma taps via __builtin_elementwise_fma.
// Rounds 14-18 measured all structural neighbors worse:
//   r14 8blk+staging: spill (WRITE 288MB);  r15 8blk no-staging: remat
//   (VGPR 28, FETCH +47%);  r16 bounds(6): identical codegen (null);
//   r17 R=4 anti-fission: +3.5 loads/row;  r18 wave-uniform rows: 3.5x
//   load redundancy (107us busy).
__global__ __launch_bounds__(256, 4) void ssim_main(
    const float* __restrict__ img1, const float* __restrict__ img2,
    float* __restrict__ partials, GaussW gw, int use_atomic, float* __restrict__ out)
{
    __shared__ vf2 VAB[TH][LDSW];   // 19200 B
    __shared__ vf2 VTS[TH][LDSW];   // 19200 B  (total 38.4 KB -> 4 blocks/CU)
    __shared__ float wsum[4];

    const int tid = threadIdx.x;
    const int plane = blockIdx.z;
    const int tr0 = blockIdx.y * TH;
    const int tc0 = blockIdx.x * TW;
    const float* __restrict__ plane1 = img1 + ((size_t)plane << 18);  // uniform -> SGPR base
    const float* __restrict__ plane2 = img2 + ((size_t)plane << 18);

    // ---------------- Phase 1: vertical conv, packed accumulator scatter ------
    // 3 chunks x 74 active threads: one lds column j (gc = tc0 + j - 5) each,
    // 11 output rows per chunk. Single code path, first-touch init.
    {
        const int j = tid % 80;       // lds col
        const int chunk = tid / 80;   // 0..2; active if chunk<3 && j<74
        if (chunk < 3 && j < 74) {
            const int r0 = chunk * 11;
            const int gc = tc0 + j - 5;
            const float cmask = ((unsigned)gc < IMG_W) ? 1.f : 0.f;
            const int gcc = min(max(gc, 0), IMG_W - 1);   // v_med3

            // ---- stage ALL loads first: one latency exposure, 42 in flight ----
            float ra[21], rb[21];
            #pragma unroll
            for (int ii = 0; ii < 21; ++ii) {
                const int gr = tr0 + r0 - 5 + ii;
                const int grc = min(max(gr, 0), IMG_H - 1);
                const uint32_t idx = (uint32_t)(grc * IMG_W + gcc);
                ra[ii] = plane1[idx];
                rb[ii] = plane2[idx];
            }
            __builtin_amdgcn_sched_barrier(0);   // pin load issue before tap stream

            vf2 aAB[11], aTS[11];
            #pragma unroll
            for (int ii = 0; ii < 21; ++ii) {
                const int gr = tr0 + r0 - 5 + ii;
                const float rmask = ((unsigned)gr < IMG_H) ? cmask : 0.f;
                const float a = ra[ii] * rmask;
                const float b = rb[ii] * rmask;
                const vf2 ab = { a, b };
                const vf2 pq = ab * ab;                    // v_pk_mul_f32
                const vf2 ts = { pq.x + pq.y, a * b };     // (a^2+b^2, a*b)
                #pragma unroll
                for (int o = 0; o < 11; ++o) {
                    if (o <= ii && ii <= o + 10) {          // compile-time predicate
                        const float wt = gw.w[ii - o];
                        const vf2 wtv = { wt, wt };
                        if (ii == o) {                       // first touch
                            aAB[o] = wtv * ab;
                            aTS[o] = wtv * ts;
                        } else {
                            aAB[o] = __builtin_elementwise_fma(wtv, ab, aAB[o]);
                            aTS[o] = __builtin_elementwise_fma(wtv, ts, aTS[o]);
                        }
                    }
                }
            }
            #pragma unroll
            for (int o = 0; o < 11; ++o) {
                const int r = r0 + o;
                if (r0 + o < TH) {   // only chunk2/o=10 is false
                    VAB[r][j] = aAB[o];        // ds_write_b64
                    VTS[r][j] = aTS[o];        // ds_write_b64
                }
            }
        }
    }
    __syncthreads();

    // ---------------- Phase 2: horizontal conv, packed per-column scatter -----
    // Row index in LOW lane bits: b64 pair (75r + c0 + k) mod 16, 75 odd ->
    // all 16 pairs x2 per half-wave = hardware minimum, conflict-free.
    float lsum = 0.f;
    {
        const int r = tid & 31;        // 0..31  (low bits!)
        const int c0 = (tid >> 5) * 8; // col group 0..7
        const vf2* __restrict__ bAB = &VAB[r][c0];
        const vf2* __restrict__ bTS = &VTS[r][c0];

        vf2 mAB[8], eTS[8];

        #pragma unroll
        for (int k = 0; k <= 17; ++k) {          // stored cols c0 .. c0+17
            const vf2 vab = bAB[k];              // ds_read_b64, immediate offset
            const vf2 vts = bTS[k];              // ds_read_b64
            #pragma unroll
            for (int c = 0; c < 8; ++c) {
                if (k - 10 <= c && c <= k) {                // compile-time
                    const float wt = gw.w[k - c];
                    const vf2 wtv = { wt, wt };
                    if (k == c) {                            // first touch (tap 0)
                        mAB[c] = wtv * vab;
                        eTS[c] = wtv * vts;
                    } else {
                        mAB[c] = __builtin_elementwise_fma(wtv, vab, mAB[c]);
                        eTS[c] = __builtin_elementwise_fma(wtv, vts, eTS[c]);
                    }
                }
            }
        }
        #pragma unroll
        for (int c = 0; c < 8; ++c) {
            const float a1 = mAB[c].x, a2 = mAB[c].y;   // mu1, mu2
            const float T  = eTS[c].x, S = eTS[c].y;    // conv(a^2+b^2), conv(ab)
            const float h    = fmaf(a1, a1, a2 * a2);   // mu11 + mu22
            const float mu12 = a1 * a2;
            const float num  = fmaf(2.f, mu12, 0.0001f)
                             * fmaf(2.f, S - mu12, 0.0009f);   // (2mu12+C1)(2s12+C2)
            const float den  = (h + 0.0001f) * ((T - h) + 0.0009f);
            lsum = fmaf(num, __builtin_amdgcn_rcpf(den), lsum); // rcp ~1ulp, tol 2.7e-4
        }
    }
    // block reduction
    #pragma unroll
    for (int off = 32; off; off >>= 1) lsum += __shfl_down(lsum, off, 64);
    if ((tid & 63) == 0) wsum[tid >> 6] = lsum;
    __syncthreads();
    if (tid == 0) {
        const float bs = wsum[0] + wsum[1] + wsum[2] + wsum[3];
        if (use_atomic) {
            atomicAdd(out, bs * (float)(1.0 / NPIX));
        } else {
            const int bId = (blockIdx.z * gridDim.y + blockIdx.y) * gridDim.x + blockIdx.x;
            partials[bId] = bs;
        }
    }
}

__global__ __launch_bounds__(256) void ssim_reduce(
    const float* __restrict__ partials, int n, float* __restrict__ out)
{
    const int tid = threadIdx.x;
    double s = 0.0;
    for (int i = tid; i < n; i += 256) s += (double)partials[i];
    #pragma unroll
    for (int off = 32; off; off >>= 1) s += __shfl_down(s, off, 64);
    __shared__ double ws[4];
    if ((tid & 63) == 0) ws[tid >> 6] = s;
    __syncthreads();
    if (tid == 0) out[0] = (float)(((ws[0] + ws[1]) + (ws[2] + ws[3])) / NPIX);
}

extern "C" void kernel_launch(void* const* d_in, const int* in_sizes, int n_in,
                              void* d_out, int out_size, void* d_ws, size_t ws_size,
                              hipStream_t stream) {
    const float* img1 = (const float*)d_in[0];
    const float* img2 = (const float*)d_in[1];
    float* out = (float*)d_out;

    // Gaussian window (host, double precision, normalized)
    GaussW gw;
    {
        double g[11], sum = 0.0;
        for (int i = 0; i < 11; ++i) {
            const double c = (double)(i - 5);
            g[i] = std::exp(-(c * c) / 4.5);   // 2*sigma^2 = 4.5
            sum += g[i];
        }
        for (int i = 0; i < 11; ++i) gw.w[i] = (float)(g[i] / sum);
    }

    dim3 grid(IMG_W / TW, IMG_H / TH, NPLANES);   // 8 x 16 x 96 = 12288
    const int nPart = grid.x * grid.y * grid.z;

    if (ws_size >= (size_t)nPart * sizeof(float)) {
        // deterministic two-stage reduction
        ssim_main<<<grid, 256, 0, stream>>>(img1, img2, (float*)d_ws, gw, 0, out);
        ssim_reduce<<<1, 256, 0, stream>>>((float*)d_ws, nPart, out);
    } else {
        // fallback: atomic accumulation (still within tolerance)
        hipMemsetAsync(d_out, 0, sizeof(float), stream);
        ssim_main<<<grid, 256, 0, stream>>>(img1, img2, nullptr, gw, 1, out);
    }
}